// Round 1
// baseline (81.117 us; speedup 1.0000x reference)
//
#include <hip/hip_runtime.h>

#define BLOCK 256
#define SPT 4            // source points per thread
#define MAX_CHUNK_M 512  // max targets staged in LDS per block (8 KB of float4)

// Phase 1: each block handles (batch b, source-block sblk, target-chunk c).
// Stages chunkM targets as (x,y,z,|t|^2) float4 in LDS, then each thread scans
// them for its SPT source points, tracking min of (|t|^2 - 2 s.t).
__global__ __launch_bounds__(BLOCK) void nn_partial_kernel(
    const float* __restrict__ src, const float* __restrict__ tgt,
    float* __restrict__ partial, int N, int M, int SB, int C, int chunkM, int ST)
{
    __shared__ float4 tpts[MAX_CHUNK_M];

    const int c    = blockIdx.x % C;
    const int tmp  = blockIdx.x / C;
    const int sblk = tmp % SB;
    const int b    = tmp / SB;
    const int tid  = threadIdx.x;

    // ---- stage target chunk into LDS (broadcast-read later) ----
    const int mbase = c * chunkM;
    const float* tb = tgt + (size_t)b * M * 3;
    for (int j = tid; j < chunkM; j += BLOCK) {
        int mi = mbase + j;
        float tx = 0.f, ty = 0.f, tz = 0.f;
        float t2 = 1e30f;  // out-of-range targets never win the min
        if (mi < M) {
            tx = tb[(size_t)mi * 3 + 0];
            ty = tb[(size_t)mi * 3 + 1];
            tz = tb[(size_t)mi * 3 + 2];
            t2 = fmaf(tx, tx, fmaf(ty, ty, tz * tz));
        }
        tpts[j] = make_float4(tx, ty, tz, t2);
    }
    __syncthreads();

    // ---- load this thread's source points, pre-scaled by -2 ----
    const int sbase = sblk * (BLOCK * SPT);
    const float* sbp = src + (size_t)b * N * 3;
    float nsx[SPT], nsy[SPT], nsz[SPT], mind[SPT];
#pragma unroll
    for (int s = 0; s < SPT; ++s) {
        int si = sbase + tid + s * BLOCK;
        float x = 0.f, y = 0.f, z = 0.f;
        if (si < N) {
            x = sbp[(size_t)si * 3 + 0];
            y = sbp[(size_t)si * 3 + 1];
            z = sbp[(size_t)si * 3 + 2];
        }
        nsx[s] = -2.f * x;
        nsy[s] = -2.f * y;
        nsz[s] = -2.f * z;
        mind[s] = 1e30f;
    }

    // ---- main loop: broadcast LDS float4 reads, 4 VALU ops per pair ----
#pragma unroll 4
    for (int m = 0; m < chunkM; ++m) {
        float4 tp = tpts[m];
#pragma unroll
        for (int s = 0; s < SPT; ++s) {
            float d = fmaf(nsx[s], tp.x, tp.w);
            d = fmaf(nsy[s], tp.y, d);
            d = fmaf(nsz[s], tp.z, d);
            mind[s] = fminf(mind[s], d);
        }
    }

    // ---- write partial mins: layout [c][global_source] for coalescing ----
#pragma unroll
    for (int s = 0; s < SPT; ++s) {
        int si = sbase + tid + s * BLOCK;
        if (si < N) {
            partial[(size_t)c * ST + (size_t)b * N + si] = mind[s];
        }
    }
}

// Phase 2: per source, min over chunks, add |s|^2, block-reduce sum, atomicAdd.
__global__ __launch_bounds__(BLOCK) void nn_reduce_kernel(
    const float* __restrict__ src, const float* __restrict__ partial,
    float* __restrict__ out, int ST, int C, float scale)
{
    const int i = blockIdx.x * BLOCK + threadIdx.x;
    float v = 0.f;
    if (i < ST) {
        float sx = src[(size_t)i * 3 + 0];
        float sy = src[(size_t)i * 3 + 1];
        float sz = src[(size_t)i * 3 + 2];
        float mind = 1e30f;
        for (int c = 0; c < C; ++c) {
            mind = fminf(mind, partial[(size_t)c * ST + i]);
        }
        v = fmaf(sx, sx, fmaf(sy, sy, sz * sz)) + mind;  // = min ||s - t||^2
    }

    // wave (64-lane) butterfly reduce
#pragma unroll
    for (int off = 32; off > 0; off >>= 1) {
        v += __shfl_xor(v, off, 64);
    }

    __shared__ float wsum[BLOCK / 64];
    const int lane = threadIdx.x & 63;
    const int wav  = threadIdx.x >> 6;
    if (lane == 0) wsum[wav] = v;
    __syncthreads();
    if (threadIdx.x == 0) {
        float s = 0.f;
#pragma unroll
        for (int w = 0; w < BLOCK / 64; ++w) s += wsum[w];
        atomicAdd(out, s * scale);
    }
}

extern "C" void kernel_launch(void* const* d_in, const int* in_sizes, int n_in,
                              void* d_out, int out_size, void* d_ws, size_t ws_size,
                              hipStream_t stream) {
    const float* src = (const float*)d_in[0];  // [B, N, 3] fp32
    const float* tgt = (const float*)d_in[1];  // [B, M, 3] fp32
    float* out = (float*)d_out;                // scalar fp32

    const int B = 2;
    const int N = in_sizes[0] / (B * 3);
    const int M = in_sizes[1] / (B * 3);
    const int ST = B * N;

    // choose target-chunk count: prefer 32 (chunkM=256, 512 blocks), but
    // respect ws capacity and LDS staging limit.
    int C = 32;
    while (C > 1 && (size_t)C * ST * sizeof(float) > ws_size) C >>= 1;
    int chunkM = (M + C - 1) / C;
    while (chunkM > MAX_CHUNK_M) { C <<= 1; chunkM = (M + C - 1) / C; }

    const int SB = (N + BLOCK * SPT - 1) / (BLOCK * SPT);
    float* partial = (float*)d_ws;

    hipMemsetAsync(d_out, 0, sizeof(float), stream);

    dim3 grid1(B * SB * C);
    nn_partial_kernel<<<grid1, BLOCK, 0, stream>>>(src, tgt, partial,
                                                   N, M, SB, C, chunkM, ST);

    dim3 grid2((ST + BLOCK - 1) / BLOCK);
    nn_reduce_kernel<<<grid2, BLOCK, 0, stream>>>(src, partial, out,
                                                  ST, C, 1.0f / (3.0f * N * B));
}